// Round 2
// baseline (978.894 us; speedup 1.0000x reference)
//
#include <hip/hip_runtime.h>
#include <stdint.h>

#define NB      256                 // batch
#define HH      512
#define WW      512
#define HWSZ    (HH * WW)           // 262144 floats per plane
#define SPLIT   16                  // blocks per batch
#define THREADS 256
#define F4_PER_BLOCK (HWSZ / 4 / SPLIT)     // 4096 float4 per block
#define ITERS        (F4_PER_BLOCK / THREADS) // 16

// Workspace layout (zeroed by a 1-node memset each call)
struct Ws {
  unsigned long long keys[NB];   // packed (valbits<<32)|~idx, atomicMax
  int                cnt[NB];    // per-batch arrival counters
  int                done;       // global arrival counter
  int                pad;
  double             acc;        // global fp64 accumulator
};

__device__ __forceinline__ float block_reduce_sum(float v, float* lds) {
  const int lane = threadIdx.x & 63, wave = threadIdx.x >> 6;
  #pragma unroll
  for (int off = 32; off > 0; off >>= 1) v += __shfl_down(v, off, 64);
  if (lane == 0) lds[wave] = v;
  __syncthreads();
  float s = 0.0f;
  if (threadIdx.x == 0) {
    #pragma unroll
    for (int i = 0; i < THREADS / 64; ++i) s += lds[i];
  }
  __syncthreads();   // lds reusable after
  return s;          // valid in thread 0 only
}

// Single fused dispatch: stream+argmax -> (last block per batch) window
// correction -> (last block overall) finalize. No spin-waits; all
// cross-block communication via device-scope atomics + threadfence.
__global__ __launch_bounds__(THREADS) void fused_kernel(
    const float* __restrict__ outp, const float* __restrict__ tgt,
    Ws* __restrict__ ws, float* __restrict__ out) {
  const int blk   = blockIdx.x;
  const int b     = blk >> 4;          // / SPLIT
  const int chunk = blk & (SPLIT - 1);
  const size_t base4 = (size_t)b * (HWSZ / 4) + (size_t)chunk * F4_PER_BLOCK;
  const float4* o4 = (const float4*)outp + base4;
  const float4* t4 = (const float4*)tgt  + base4;

  const int t = threadIdx.x;
  float    sum     = 0.0f;
  float    bestv   = -1.0f;            // targets are >= 0 -> always overwritten
  unsigned bestidx = 0u;

  #pragma unroll
  for (int i = 0; i < ITERS; ++i) {    // coalesced, idx increases per thread
    const int p = i * THREADS + t;
    const float4 ov = o4[p];
    const float4 tv = t4[p];
    const float d0 = ov.x - tv.x, d1 = ov.y - tv.y;
    const float d2 = ov.z - tv.z, d3 = ov.w - tv.w;
    sum += d0 * d0 + d1 * d1 + d2 * d2 + d3 * d3;
    const unsigned fi = (unsigned)((chunk * F4_PER_BLOCK + p) * 4);
    if (tv.x > bestv) { bestv = tv.x; bestidx = fi;     }  // strict '>': first max
    if (tv.y > bestv) { bestv = tv.y; bestidx = fi + 1; }
    if (tv.z > bestv) { bestv = tv.z; bestidx = fi + 2; }
    if (tv.w > bestv) { bestv = tv.w; bestidx = fi + 3; }
  }

  // pack: high 32 = float bits (nonneg => order-preserving), low 32 = ~idx
  unsigned long long key =
      ((unsigned long long)__float_as_uint(bestv) << 32) | (unsigned long long)(~bestidx);

  __shared__ float              s_sum[THREADS / 64];
  __shared__ unsigned long long s_keys[THREADS / 64];
  __shared__ int                s_last;
  __shared__ unsigned long long s_key;

  const int lane = t & 63, wave = t >> 6;
  #pragma unroll
  for (int off = 32; off > 0; off >>= 1) {
    unsigned long long ok = __shfl_down(key, off, 64);
    if (ok > key) key = ok;
    sum += __shfl_down(sum, off, 64);
  }
  if (lane == 0) { s_keys[wave] = key; s_sum[wave] = sum; }
  __syncthreads();

  if (t == 0) {
    unsigned long long k = s_keys[0];
    float s = s_sum[0];
    #pragma unroll
    for (int i = 1; i < THREADS / 64; ++i) {
      if (s_keys[i] > k) k = s_keys[i];
      s += s_sum[i];
    }
    atomicMax(&ws->keys[b], k);
    atomicAdd(&ws->acc, (double)s);
    __threadfence();                              // release before arrival
    s_last = atomicAdd(&ws->cnt[b], 1);
  }
  __syncthreads();

  if (s_last != SPLIT - 1) return;                // not the last arriver for batch b

  // ---- last block of batch b: window correction (inputs are L2-hot) ----
  __threadfence();                                // acquire after arrival
  if (t == 0) s_key = atomicMax(&ws->keys[b], 0ull);  // device-scope fresh read
  __syncthreads();
  const unsigned long long k = s_key;
  const float maxv = __uint_as_float((unsigned)(k >> 32));

  float corr = 0.0f;
  if (maxv >= 0.5f) {
    const unsigned idx = ~(unsigned)(k & 0xFFFFFFFFull);
    const int ph = (int)(idx / WW), pw = (int)(idx % WW);
    const int dh = HH / 16, dw = WW / 16;                 // 32, 32
    const int top  = max(ph - dh, 0), bot   = min(ph + dh, HH);
    const int left = max(pw - dw, 0), right = min(pw + dw, WW);
    const int Lh = bot - top, Lw = right - left;          // each in [32, 64]
    const float nh = (float)max((Lh + 1) / 2 - 1, 1);     // linspace denom
    const float nw = (float)max((Lw + 1) / 2 - 1, 1);
    const float* ob = outp + (size_t)b * HWSZ;
    const float* tb = tgt  + (size_t)b * HWSZ;
    const int n_elems = Lh * Lw;                          // <= 4096
    for (int j = t; j < n_elems; j += THREADS) {
      const int r = j / Lw, c = j % Lw;
      const int kr = min(r, Lh - 1 - r), kc = min(c, Lw - 1 - c);
      const float vh = 1.0f + 9.0f * (float)kr / nh;
      const float vw = 1.0f + 9.0f * (float)kc / nw;
      const int row = top + r, col = left + c;
      const float d = ob[row * WW + col] - tb[row * WW + col];
      corr += (vh * vw - 1.0f) * d * d;
    }
  }
  const float corr_total = block_reduce_sum(corr, s_sum);

  if (t == 0) {
    atomicAdd(&ws->acc, (double)corr_total);
    __threadfence();                              // release before arrival
    const int d = atomicAdd(&ws->done, 1);
    if (d == NB - 1) {                            // last batch finisher overall
      __threadfence();                            // acquire
      const double total = atomicAdd(&ws->acc, 0.0);   // device-scope fresh read
      out[0] = (float)(total / (double)((size_t)NB * HWSZ));
    }
  }
}

extern "C" void kernel_launch(void* const* d_in, const int* in_sizes, int n_in,
                              void* d_out, int out_size, void* d_ws, size_t ws_size,
                              hipStream_t stream) {
  const float* outp = (const float*)d_in[0];   // "output"
  const float* tgt  = (const float*)d_in[1];   // "target"
  Ws* ws = (Ws*)d_ws;

  // ws is poisoned 0xAA before every timed call — zero the control block.
  hipMemsetAsync(d_ws, 0, sizeof(Ws), stream);

  fused_kernel<<<NB * SPLIT, THREADS, 0, stream>>>(outp, tgt, ws, (float*)d_out);
}

// Round 3
// 510.379 us; speedup vs baseline: 1.9180x; 1.9180x over previous
//
#include <hip/hip_runtime.h>
#include <stdint.h>

#define NB      256                 // batch
#define HH      512
#define WW      512
#define HWSZ    (HH * WW)           // 262144 floats per plane
#define SPLIT   16                  // blocks per batch in pass 1
#define NBLK1   (NB * SPLIT)        // 4096
#define THREADS 256
#define F4_PER_BLOCK (HWSZ / 4 / SPLIT)       // 4096 float4 per block
#define ITERS        (F4_PER_BLOCK / THREADS) // 16

// Workspace: all plain stores, every slot written every call (no init needed).
// Cross-kernel visibility is guaranteed by stream/graph dispatch boundaries.
struct Ws {
  unsigned long long bestkey[NBLK1];  // per-pass1-block packed (valbits<<32)|~idx
  float              partial[NBLK1];  // per-pass1-block sum of diff^2
  float              corr[NB];        // per-batch window correction
};

// ---------------- Pass 1: stream, per-block argmax + sum ----------------
__global__ __launch_bounds__(THREADS) void pass1_kernel(
    const float* __restrict__ outp, const float* __restrict__ tgt,
    Ws* __restrict__ ws) {
  const int blk   = blockIdx.x;
  const int chunk = blk & (SPLIT - 1);
  const size_t base4 = (size_t)blk * F4_PER_BLOCK;   // blk = b*SPLIT+chunk, contiguous
  const float4* o4 = (const float4*)outp + base4;
  const float4* t4 = (const float4*)tgt  + base4;

  const int t = threadIdx.x;
  float    sum     = 0.0f;
  float    bestv   = -1.0f;            // targets >= 0 -> always overwritten
  unsigned bestidx = 0u;

  #pragma unroll
  for (int i = 0; i < ITERS; ++i) {    // coalesced; idx increases per thread
    const int p = i * THREADS + t;
    const float4 ov = o4[p];
    const float4 tv = t4[p];
    const float d0 = ov.x - tv.x, d1 = ov.y - tv.y;
    const float d2 = ov.z - tv.z, d3 = ov.w - tv.w;
    sum += d0 * d0 + d1 * d1 + d2 * d2 + d3 * d3;
    const unsigned fi = (unsigned)((chunk * F4_PER_BLOCK + p) * 4); // idx in plane
    if (tv.x > bestv) { bestv = tv.x; bestidx = fi;     }  // strict '>': first max
    if (tv.y > bestv) { bestv = tv.y; bestidx = fi + 1; }
    if (tv.z > bestv) { bestv = tv.z; bestidx = fi + 2; }
    if (tv.w > bestv) { bestv = tv.w; bestidx = fi + 3; }
  }

  // pack: high 32 = float bits (nonneg => order-preserving), low 32 = ~idx
  unsigned long long key =
      ((unsigned long long)__float_as_uint(bestv) << 32) | (unsigned long long)(~bestidx);

  const int lane = t & 63, wave = t >> 6;
  #pragma unroll
  for (int off = 32; off > 0; off >>= 1) {
    unsigned long long ok = __shfl_down(key, off, 64);
    if (ok > key) key = ok;
    sum += __shfl_down(sum, off, 64);
  }
  __shared__ unsigned long long skey[THREADS / 64];
  __shared__ float              ssum[THREADS / 64];
  if (lane == 0) { skey[wave] = key; ssum[wave] = sum; }
  __syncthreads();
  if (t == 0) {
    unsigned long long k = skey[0];
    float s = ssum[0];
    #pragma unroll
    for (int i = 1; i < THREADS / 64; ++i) {
      if (skey[i] > k) k = skey[i];
      s += ssum[i];
    }
    ws->bestkey[blk] = k;    // plain stores, distinct slots — no atomics
    ws->partial[blk] = s;
  }
}

// -------- Pass 2: per-batch key merge + window correction (L2-hot) --------
__global__ __launch_bounds__(THREADS) void pass2_kernel(
    const float* __restrict__ outp, const float* __restrict__ tgt,
    Ws* __restrict__ ws) {
  const int b = blockIdx.x;
  __shared__ unsigned long long s_key;
  if (threadIdx.x == 0) {
    unsigned long long k = ws->bestkey[b * SPLIT];
    #pragma unroll
    for (int i = 1; i < SPLIT; ++i) {
      const unsigned long long ki = ws->bestkey[b * SPLIT + i];
      if (ki > k) k = ki;
    }
    s_key = k;
  }
  __syncthreads();
  const unsigned long long k = s_key;
  const float maxv = __uint_as_float((unsigned)(k >> 32));

  float corr = 0.0f;
  if (maxv >= 0.5f) {
    const unsigned idx = ~(unsigned)(k & 0xFFFFFFFFull);
    const int ph = (int)(idx / WW), pw = (int)(idx % WW);
    const int dh = HH / 16, dw = WW / 16;                 // 32, 32
    const int top  = max(ph - dh, 0), bot   = min(ph + dh, HH);
    const int left = max(pw - dw, 0), right = min(pw + dw, WW);
    const int Lh = bot - top, Lw = right - left;          // each in [32, 64]
    const float nh = (float)max((Lh + 1) / 2 - 1, 1);     // linspace denom
    const float nw = (float)max((Lw + 1) / 2 - 1, 1);
    const float* ob = outp + (size_t)b * HWSZ;
    const float* tb = tgt  + (size_t)b * HWSZ;
    const int n_elems = Lh * Lw;                          // <= 4096
    for (int j = threadIdx.x; j < n_elems; j += THREADS) {
      const int r = j / Lw, c = j % Lw;
      const int kr = min(r, Lh - 1 - r), kc = min(c, Lw - 1 - c);
      const float vh = 1.0f + 9.0f * (float)kr / nh;
      const float vw = 1.0f + 9.0f * (float)kc / nw;
      const int row = top + r, col = left + c;
      const float d = ob[row * WW + col] - tb[row * WW + col];
      corr += (vh * vw - 1.0f) * d * d;
    }
  }

  const int lane = threadIdx.x & 63, wave = threadIdx.x >> 6;
  #pragma unroll
  for (int off = 32; off > 0; off >>= 1) corr += __shfl_down(corr, off, 64);
  __shared__ float ssum[THREADS / 64];
  if (lane == 0) ssum[wave] = corr;
  __syncthreads();
  if (threadIdx.x == 0) {
    float s = 0.0f;
    #pragma unroll
    for (int i = 0; i < THREADS / 64; ++i) s += ssum[i];
    ws->corr[b] = s;                                      // plain store
  }
}

// ---------------- Finalize: one block sums everything in fp64 -------------
__global__ __launch_bounds__(THREADS) void finalize_kernel(
    const Ws* __restrict__ ws, float* __restrict__ out) {
  const int t = threadIdx.x;
  double s = 0.0;
  #pragma unroll
  for (int i = 0; i < NBLK1 / THREADS; ++i) s += (double)ws->partial[i * THREADS + t];
  s += (double)ws->corr[t];                               // NB == THREADS

  const int lane = t & 63, wave = t >> 6;
  #pragma unroll
  for (int off = 32; off > 0; off >>= 1) s += __shfl_down(s, off, 64);
  __shared__ double sd[THREADS / 64];
  if (lane == 0) sd[wave] = s;
  __syncthreads();
  if (t == 0) {
    double tot = 0.0;
    #pragma unroll
    for (int i = 0; i < THREADS / 64; ++i) tot += sd[i];
    out[0] = (float)(tot / (double)((size_t)NB * HWSZ));
  }
}

extern "C" void kernel_launch(void* const* d_in, const int* in_sizes, int n_in,
                              void* d_out, int out_size, void* d_ws, size_t ws_size,
                              hipStream_t stream) {
  const float* outp = (const float*)d_in[0];   // "output"
  const float* tgt  = (const float*)d_in[1];   // "target"
  Ws* ws = (Ws*)d_ws;

  pass1_kernel<<<NBLK1, THREADS, 0, stream>>>(outp, tgt, ws);
  pass2_kernel<<<NB, THREADS, 0, stream>>>(outp, tgt, ws);
  finalize_kernel<<<1, THREADS, 0, stream>>>(ws, (float*)d_out);
}